// Round 9
// baseline (698.061 us; speedup 1.0000x reference)
//
#include <hip/hip_runtime.h>
#include <hip/hip_bf16.h>
#include <math.h>

#define D_MODEL 1024
#define D_STATE 16
#define D_CONV 4
#define D_INNER 2048
#define DT_RANK 64
#define L_SEQ 2048
#define N_BATCH 2
#define M_ROWS (N_BATCH * L_SEQ)   // 4096

#define N_CHUNK 32                 // chunks over L
#define CLEN (L_SEQ / N_CHUNK)     // 64 timesteps per chunk

#define XP_KSPLIT 8
#define XP_KLEN (D_INNER / XP_KSPLIT)  // 256
#define OP_KSPLIT 2
#define OP_KLEN (D_INNER / OP_KSPLIT)  // 1024

typedef __attribute__((ext_vector_type(8))) __bf16 bf16x8;
typedef __attribute__((ext_vector_type(4))) float f32x4;

__device__ __forceinline__ unsigned short f2b(float f) {
    unsigned int u = __float_as_uint(f);
    unsigned int r = (u + 0x7fffu + ((u >> 16) & 1u)) >> 16;   // RNE
    return (unsigned short)r;
}
__device__ __forceinline__ float b2f(unsigned short s) {
    return __uint_as_float((unsigned int)s << 16);
}
// fast softplus: max(x,0) + log(1+exp(-|x|)), branch-free
__device__ __forceinline__ float softplus_fast(float x) {
    const float ax = fabsf(x);
    return fmaxf(x, 0.f) + __logf(1.f + __expf(-ax));
}
__device__ __forceinline__ float aload(const float* p) {
    return __hip_atomic_load(p, __ATOMIC_RELAXED, __HIP_MEMORY_SCOPE_AGENT);
}

// addrspace casts for global_load_lds
#define AS1G(p) ((const __attribute__((address_space(1))) void*)(uintptr_t)(p))
#define AS3L(p) ((__attribute__((address_space(3))) void*)(unsigned int)(uintptr_t)(p))

// ---------------------------------------------------------------------------
// Fused fp32 -> bf16 cast of all tensors + flag clear (one launch).
// x_proj_w is padded 96 -> 128 rows (zeros).
// ---------------------------------------------------------------------------
#define N4_HS (M_ROWS * D_MODEL / 4)          // 1048576
#define N4_IP (2 * D_INNER * D_MODEL / 4)     // 2097152
#define N4_OP (D_MODEL * D_INNER / 4)         // 524288
#define N4_XP (128 * D_INNER / 4)             // 65536 (padded)
#define N4_DT (D_INNER * DT_RANK / 4)         // 32768
#define N4_FLAG 128                           // 512 ints as int4
#define N4_ALL (N4_HS + N4_IP + N4_OP + N4_XP + N4_DT + N4_FLAG)

__device__ __forceinline__ void cvt4(const float* s, unsigned short* d, int i) {
    const float4 f = ((const float4*)s)[i];
    ushort4 o;
    o.x = f2b(f.x); o.y = f2b(f.y); o.z = f2b(f.z); o.w = f2b(f.w);
    ((ushort4*)d)[i] = o;
}

__global__ __launch_bounds__(256) void cvt_all_kernel(
    const float* __restrict__ hs,  const float* __restrict__ ipw,
    const float* __restrict__ opw, const float* __restrict__ xpw,
    const float* __restrict__ dtw,
    unsigned short* __restrict__ hs_bf,  unsigned short* __restrict__ ipw_bf,
    unsigned short* __restrict__ opw_bf, unsigned short* __restrict__ xpw_bf,
    unsigned short* __restrict__ dtw_bf, int* __restrict__ flags)
{
    int i = blockIdx.x * 256 + threadIdx.x;
    if (i < N4_HS) { cvt4(hs, hs_bf, i); return; }
    i -= N4_HS;
    if (i < N4_IP) { cvt4(ipw, ipw_bf, i); return; }
    i -= N4_IP;
    if (i < N4_OP) { cvt4(opw, opw_bf, i); return; }
    i -= N4_OP;
    if (i < N4_XP) {
        const int row = (i * 4) >> 11;   // /2048
        ushort4 o;
        if (row < 96) {
            const float4 f = ((const float4*)xpw)[i];
            o.x = f2b(f.x); o.y = f2b(f.y); o.z = f2b(f.z); o.w = f2b(f.w);
        } else { o.x = o.y = o.z = o.w = 0; }
        ((ushort4*)xpw_bf)[i] = o;
        return;
    }
    i -= N4_XP;
    if (i < N4_DT) { cvt4(dtw, dtw_bf, i); return; }
    i -= N4_DT;
    if (i < N4_FLAG) ((int4*)flags)[i] = make_int4(0, 0, 0, 0);
}

// ---------------------------------------------------------------------------
// bf16 MFMA GEMM (m97 structure): C[M,N] = A[M,K]*B[N,K]^T.
// MODE 0: plain.  MODE 1: softplus(acc + bias[col]).
// LAYOUT 0: CT out (fp32 partials), row-major.
// LAYOUT 1: bf16 out, m4-interleaved: off(m,c) = ((m>>2)*N + c)*4 + (m&3)
//           -> each lane's 4-row acc column packs into ONE coalesced b64 store.
// Split-K: blockIdx.z selects K-chunk, C += z*M*N (LAYOUT 0 only).
// ---------------------------------------------------------------------------
template <int MODE, int LAYOUT, typename CT>
__global__ __launch_bounds__(256) void gemm_mfma_bt(
    const unsigned short* __restrict__ A, const unsigned short* __restrict__ B,
    CT* __restrict__ C, const float* __restrict__ bias,
    int M, int N, int K, int k_len)
{
    __shared__ unsigned short As[128 * 32];
    __shared__ unsigned short Bs[128 * 32];

    const int tid  = threadIdx.x;
    const int wave = tid >> 6;
    const int lane = tid & 63;
    const int row0 = blockIdx.y * 128;
    const int col0 = blockIdx.x * 128;
    const int kbeg = blockIdx.z * k_len;
    C += (size_t)blockIdx.z * M * N;
    const int wr = (wave >> 1) * 64;
    const int wc = (wave & 1) * 64;
    const int lm = lane & 15;
    const int kg = (lane >> 4) * 8;

    f32x4 acc[4][4];
    #pragma unroll
    for (int i = 0; i < 4; ++i)
        #pragma unroll
        for (int j = 0; j < 4; ++j)
            acc[i][j] = (f32x4){0.f, 0.f, 0.f, 0.f};

    const int c0 = tid;
    const int c1 = tid + 256;
    const int r0_ = c0 >> 2, kq0 = (c0 & 3) * 8;
    const int r1_ = c1 >> 2, kq1 = (c1 & 3) * 8;
    unsigned short* lA0 = As + wave * 512;
    unsigned short* lA1 = As + 2048 + wave * 512;
    unsigned short* lB0 = Bs + wave * 512;
    unsigned short* lB1 = Bs + 2048 + wave * 512;

    for (int k0 = kbeg; k0 < kbeg + k_len; k0 += 32) {
        __syncthreads();
        __builtin_amdgcn_global_load_lds(AS1G(A + (size_t)(row0 + r0_) * K + k0 + kq0), AS3L(lA0), 16, 0, 0);
        __builtin_amdgcn_global_load_lds(AS1G(A + (size_t)(row0 + r1_) * K + k0 + kq1), AS3L(lA1), 16, 0, 0);
        __builtin_amdgcn_global_load_lds(AS1G(B + (size_t)(col0 + r0_) * K + k0 + kq0), AS3L(lB0), 16, 0, 0);
        __builtin_amdgcn_global_load_lds(AS1G(B + (size_t)(col0 + r1_) * K + k0 + kq1), AS3L(lB1), 16, 0, 0);
        __syncthreads();

        bf16x8 af[4], bf[4];
        #pragma unroll
        for (int i = 0; i < 4; ++i) {
            af[i] = *(const bf16x8*)&As[(wr + i * 16 + lm) * 32 + kg];
            bf[i] = *(const bf16x8*)&Bs[(wc + i * 16 + lm) * 32 + kg];
        }
        #pragma unroll
        for (int i = 0; i < 4; ++i)
            #pragma unroll
            for (int j = 0; j < 4; ++j)
                acc[i][j] = __builtin_amdgcn_mfma_f32_16x16x32_bf16(af[i], bf[j], acc[i][j], 0, 0, 0);
    }

    // C/D mapping: col = lane&15, row = (lane>>4)*4 + reg
    const int quad = lane >> 4;
    if constexpr (LAYOUT == 1) {
        #pragma unroll
        for (int i = 0; i < 4; ++i) {
            const int r4 = (row0 + wr + i * 16) / 4 + quad;   // row>>2
            #pragma unroll
            for (int j = 0; j < 4; ++j) {
                const int cc = col0 + wc + j * 16 + lm;
                const float bv = (MODE == 1) ? bias[cc] : 0.f;
                float v0 = acc[i][j][0], v1 = acc[i][j][1];
                float v2 = acc[i][j][2], v3 = acc[i][j][3];
                if (MODE == 1) {
                    v0 = softplus_fast(v0 + bv); v1 = softplus_fast(v1 + bv);
                    v2 = softplus_fast(v2 + bv); v3 = softplus_fast(v3 + bv);
                }
                ushort4 o;
                o.x = f2b(v0); o.y = f2b(v1); o.z = f2b(v2); o.w = f2b(v3);
                *(ushort4*)((unsigned short*)C + ((size_t)r4 * N + cc) * 4) = o;
            }
        }
    } else {
        #pragma unroll
        for (int j = 0; j < 4; ++j) {
            const int cc = col0 + wc + j * 16 + lm;
            const float bv = (MODE == 1) ? bias[cc] : 0.f;
            #pragma unroll
            for (int i = 0; i < 4; ++i) {
                const int r = row0 + wr + i * 16 + quad * 4;
                #pragma unroll
                for (int v = 0; v < 4; ++v) {
                    float val = acc[i][j][v];
                    if (MODE == 1) val = softplus_fast(val + bv);
                    C[(size_t)(r + v) * N + cc] = (CT)val;
                }
            }
        }
    }
}

// reduce x_proj split-K partials [XP_KSPLIT][M][128] -> xdbl [M][96] fp32
// and dt_bf [M][64] bf16.
__global__ __launch_bounds__(256) void xproj_reduce_kernel(
    const float* __restrict__ part, float* __restrict__ xdbl,
    unsigned short* __restrict__ dt_bf)
{
    const int i = blockIdx.x * 256 + threadIdx.x;   // over M * 24
    if (i >= M_ROWS * 24) return;
    const int m  = i / 24;
    const int j4 = (i - m * 24) * 4;
    f32x4 s = *(const f32x4*)(part + (size_t)m * 128 + j4);
    #pragma unroll
    for (int ks = 1; ks < XP_KSPLIT; ++ks)
        s += *(const f32x4*)(part + (size_t)ks * M_ROWS * 128 + (size_t)m * 128 + j4);
    *(f32x4*)(xdbl + (size_t)m * 96 + j4) = s;
    if (j4 < DT_RANK) {
        ushort4 o;
        o.x = f2b(s.x); o.y = f2b(s.y); o.z = f2b(s.z); o.w = f2b(s.w);
        *(ushort4*)(dt_bf + (size_t)m * DT_RANK + j4) = o;
    }
}

// reduce out_proj split-K partials [OP_KSPLIT][M][D_MODEL] -> out (fp32)
__global__ __launch_bounds__(256) void oproj_reduce_kernel(
    const float* __restrict__ part, float* __restrict__ out)
{
    const int i = blockIdx.x * 256 + threadIdx.x;   // over M*D_MODEL/4
    if (i >= M_ROWS * D_MODEL / 4) return;
    f32x4 s = ((const f32x4*)part)[i];
    #pragma unroll
    for (int ks = 1; ks < OP_KSPLIT; ++ks)
        s += ((const f32x4*)part)[(size_t)ks * (M_ROWS * D_MODEL / 4) + i];
    ((f32x4*)out)[i] = s;
}

// ---------------------------------------------------------------------------
// Depthwise causal conv (width 4) + bias + SiLU.  Reads x half of the
// m4-interleaved xz; writes u row-major bf16.
// ---------------------------------------------------------------------------
__global__ __launch_bounds__(256) void conv_silu_kernel(
    const unsigned short* __restrict__ xz_il, const float* __restrict__ conv_w,
    const float* __restrict__ conv_b, unsigned short* __restrict__ u_bf)
{
    const int idx = blockIdx.x * 256 + threadIdx.x;
    const int c  = idx & (D_INNER - 1);
    const int ml = idx >> 11;
    const int l  = ml & (L_SEQ - 1);
    float acc = conv_b[c];
    const float* w = conv_w + c * D_CONV;
    #pragma unroll
    for (int j = 0; j < D_CONV; ++j) {
        const int ll = l - (D_CONV - 1) + j;
        if (ll >= 0) {
            const int mm = ml - (D_CONV - 1) + j;
            const size_t off = ((size_t)(mm >> 2) * (2 * D_INNER) + c) * 4 + (mm & 3);
            acc = fmaf(b2f(xz_il[off]), w[j], acc);
        }
    }
    const float uv = acc / (1.f + __expf(-acc));
    u_bf[(size_t)ml * D_INNER + c] = f2b(uv);
}

// ---------------------------------------------------------------------------
// Single-pass fused selective scan with decoupled lookback.
// One lane owns one d channel + 16 states in registers.  Phase 0: local
// (P=prod dA, Q=scan from 0) -> publish PARTIAL.  Lookback composes
// predecessors (chunk 0 publishes INCLUSIVE unconditionally -> guaranteed
// progress, no co-residency needed).  Publish INCLUSIVE.  Phase 1: replay
// from h_in (L2-warm re-reads), emit gated y.
// delta: m4-interleaved bf16; u/y row-major bf16; z from interleaved xz.
// ---------------------------------------------------------------------------
__global__ __launch_bounds__(256) void scan_fused_kernel(
    const unsigned short* __restrict__ delta_il,
    const unsigned short* __restrict__ u_bf,
    const float* __restrict__ xdbl,
    const unsigned short* __restrict__ xz_il,
    const float* __restrict__ A_log, const float* __restrict__ Dp,
    float* __restrict__ P, float* __restrict__ Q, float* __restrict__ H,
    int* __restrict__ flags, unsigned short* __restrict__ y)
{
    const int bid  = blockIdx.x;
    const int c    = bid & (N_CHUNK - 1);
    const int rest = bid >> 5;
    const int b    = rest >> 3;
    const int dgrp = rest & 7;
    const int d    = dgrp * 256 + threadIdx.x;
    const int t0   = c * CLEN;
    const int fbase = (b * 8 + dgrp) * N_CHUNK;

    float nA[16];
    #pragma unroll
    for (int k = 0; k < 4; ++k) {
        const float4 a4 = *(const float4*)(A_log + (size_t)d * 16 + k * 4);
        nA[4 * k + 0] = -__expf(a4.x);
        nA[4 * k + 1] = -__expf(a4.y);
        nA[4 * k + 2] = -__expf(a4.z);
        nA[4 * k + 3] = -__expf(a4.w);
    }

    // ---- phase 0: local scan from zero ----
    float h[16], Pacc[16];
    #pragma unroll
    for (int n = 0; n < 16; ++n) { h[n] = 0.f; Pacc[n] = 1.f; }

    for (int t = 0; t < CLEN; ++t) {
        const size_t m = (size_t)b * L_SEQ + t0 + t;
        const float dt_v = b2f(delta_il[((m >> 2) * D_INNER + d) * 4 + (m & 3)]);
        const float u_v  = b2f(u_bf[m * D_INNER + d]);
        const float dtu  = dt_v * u_v;
        const float* sB = xdbl + m * 96 + DT_RANK;   // wave-uniform -> s_load
        #pragma unroll
        for (int n = 0; n < 16; ++n) {
            const float dA = __expf(dt_v * nA[n]);
            Pacc[n] *= dA;
            h[n] = fmaf(dA, h[n], dtu * sB[n]);
        }
    }

    const size_t sbase = (((size_t)(b * N_CHUNK + c)) << 15) + ((size_t)d << 4);
    float h_in[16];

    if (c == 0) {
        #pragma unroll
        for (int k = 0; k < 4; ++k)
            *(float4*)(H + sbase + k * 4) =
                make_float4(h[4*k], h[4*k+1], h[4*k+2], h[4*k+3]);
        __threadfence();
        __syncthreads();
        if (threadIdx.x == 0)
            __hip_atomic_store(&flags[fbase], 2, __ATOMIC_RELEASE, __HIP_MEMORY_SCOPE_AGENT);
        #pragma unroll
        for (int n = 0; n < 16; ++n) h_in[n] = 0.f;
    } else {
        #pragma unroll
        for (int k = 0; k < 4; ++k) {
            *(float4*)(P + sbase + k * 4) =
                make_float4(Pacc[4*k], Pacc[4*k+1], Pacc[4*k+2], Pacc[4*k+3]);
            *(float4*)(Q + sbase + k * 4) =
                make_float4(h[4*k], h[4*k+1], h[4*k+2], h[4*k+3]);
        }
        __threadfence();
        __syncthreads();
        if (threadIdx.x == 0)
            __hip_atomic_store(&flags[fbase + c], 1, __ATOMIC_RELEASE, __HIP_MEMORY_SCOPE_AGENT);

        // decoupled lookback (per-thread walk)
        float sc[16];
        #pragma unroll
        for (int n = 0; n < 16; ++n) { h_in[n] = 0.f; sc[n] = 1.f; }
        int j = c - 1;
        while (true) {
            int f;
            while ((f = __hip_atomic_load(&flags[fbase + j], __ATOMIC_ACQUIRE,
                                          __HIP_MEMORY_SCOPE_AGENT)) == 0)
                __builtin_amdgcn_s_sleep(1);
            const size_t ob = (((size_t)(b * N_CHUNK + j)) << 15) + ((size_t)d << 4);
            if (f == 2) {
                #pragma unroll
                for (int n = 0; n < 16; ++n)
                    h_in[n] = fmaf(sc[n], aload(&H[ob + n]), h_in[n]);
                break;
            }
            #pragma unroll
            for (int n = 0; n < 16; ++n)
                h_in[n] = fmaf(sc[n], aload(&Q[ob + n]), h_in[n]);
            #pragma unroll
            for (int n = 0; n < 16; ++n)
                sc[n] *= aload(&P[ob + n]);
            --j;
        }
        // publish inclusive
        #pragma unroll
        for (int k = 0; k < 4; ++k) {
            float4 o;
            o.x = fmaf(Pacc[4*k+0], h_in[4*k+0], h[4*k+0]);
            o.y = fmaf(Pacc[4*k+1], h_in[4*k+1], h[4*k+1]);
            o.z = fmaf(Pacc[4*k+2], h_in[4*k+2], h[4*k+2]);
            o.w = fmaf(Pacc[4*k+3], h_in[4*k+3], h[4*k+3]);
            *(float4*)(H + sbase + k * 4) = o;
        }
        __threadfence();
        __syncthreads();
        if (threadIdx.x == 0)
            __hip_atomic_store(&flags[fbase + c], 2, __ATOMIC_RELEASE, __HIP_MEMORY_SCOPE_AGENT);
    }

    // ---- phase 1: replay from h_in, emit y ----
    const float Dd = Dp[d];
    #pragma unroll
    for (int n = 0; n < 16; ++n) h[n] = h_in[n];

    for (int t = 0; t < CLEN; ++t) {
        const size_t m = (size_t)b * L_SEQ + t0 + t;
        const float dt_v = b2f(delta_il[((m >> 2) * D_INNER + d) * 4 + (m & 3)]);
        const float u_v  = b2f(u_bf[m * D_INNER + d]);
        const float dtu  = dt_v * u_v;
        const float* sB = xdbl + m * 96 + DT_RANK;
        const float* sC = sB + D_STATE;

        float v = u_v * Dd;
        #pragma unroll
        for (int n = 0; n < 16; ++n) {
            const float dA = __expf(dt_v * nA[n]);
            h[n] = fmaf(dA, h[n], dtu * sB[n]);
            v = fmaf(h[n], sC[n], v);
        }
        const float z = b2f(xz_il[((m >> 2) * (2 * D_INNER) + D_INNER + d) * 4 + (m & 3)]);
        const float sig = 1.f / (1.f + __expf(-z));
        y[m * D_INNER + d] = f2b(v * z * sig);
    }
}

// ---------------------------------------------------------------------------
// Launch
// ---------------------------------------------------------------------------
extern "C" void kernel_launch(void* const* d_in, const int* in_sizes, int n_in,
                              void* d_out, int out_size, void* d_ws, size_t ws_size,
                              hipStream_t stream)
{
    const float* hs        = (const float*)d_in[0];
    const float* in_proj_w = (const float*)d_in[1];
    const float* conv_w    = (const float*)d_in[2];
    const float* conv_b    = (const float*)d_in[3];
    const float* x_proj_w  = (const float*)d_in[4];
    const float* dt_proj_w = (const float*)d_in[5];
    const float* dt_proj_b = (const float*)d_in[6];
    const float* A_log     = (const float*)d_in[7];
    const float* D_param   = (const float*)d_in[8];
    const float* out_proj_w= (const float*)d_in[9];
    float* out = (float*)d_out;

    // ---- workspace layout ----
    unsigned short* xz_il = (unsigned short*)d_ws;                       // 33.5MB (interleaved)
    unsigned short* u_bf  = xz_il + (size_t)M_ROWS * 2 * D_INNER;        // 16.8MB
    float* xdbl           = (float*)(u_bf + (size_t)M_ROWS * D_INNER);   // 1.6MB
    unsigned short* dt_bf = (unsigned short*)(xdbl + (size_t)M_ROWS * 96); // 0.5MB
    float* delta_region   = (float*)(dt_bf + (size_t)M_ROWS * DT_RANK);  // reserve 33.5MB
    unsigned short* delta_il = (unsigned short*)delta_region;            // uses 16.8MB (interleaved)
    float* Pws = delta_region + (size_t)M_ROWS * D_INNER;                // 8.4MB
    float* Qws = Pws + (size_t)N_BATCH * N_CHUNK * D_INNER * 16;         // 8.4MB
    float* Hws = Qws + (size_t)N_BATCH * N_CHUNK * D_INNER * 16;         // 8.4MB
    unsigned short* opw_bf = (unsigned short*)(Hws + (size_t)N_BATCH * N_CHUNK * D_INNER * 16);
    unsigned short* y_bf   = opw_bf + (size_t)D_MODEL * D_INNER;         // 16.8MB
    unsigned short* xpw_bf = y_bf   + (size_t)M_ROWS * D_INNER;          // 0.5MB
    unsigned short* dtw_bf = xpw_bf + (size_t)128 * D_INNER;             // 0.26MB
    int* flags             = (int*)(dtw_bf + (size_t)D_INNER * DT_RANK); // 2KB
    // aliases (stream-ordered, non-overlapping lifetimes):
    unsigned short* hs_bf  = (unsigned short*)delta_region;      // dead after in_proj (25.2MB<=33.5)
    unsigned short* ipw_bf = hs_bf + (size_t)M_ROWS * D_MODEL;
    float* xp_part = (float*)y_bf;     // [8][4096][128] f32 = 16.8MB, dead after xproj_reduce
    float* op_part = (float*)xz_il;    // [2][4096][1024] f32 = 33.5MB, xz dead after scan

    const dim3 blk(256);

    // 0) fused casts + flag clear
    cvt_all_kernel<<<(N4_ALL + 255) / 256, blk, 0, stream>>>(
        hs, in_proj_w, out_proj_w, x_proj_w, dt_proj_w,
        hs_bf, ipw_bf, opw_bf, xpw_bf, dtw_bf, flags);

    // 1) xz = hs @ in_proj_w^T   (bf16 MFMA, interleaved bf16 out)
    gemm_mfma_bt<0, 1, unsigned short>
        <<<dim3((2 * D_INNER) / 128, M_ROWS / 128, 1), blk, 0, stream>>>(
        hs_bf, ipw_bf, xz_il, nullptr, M_ROWS, 2 * D_INNER, D_MODEL, D_MODEL);

    // 2) u = silu(causal_conv(x) + conv_b)
    conv_silu_kernel<<<(M_ROWS * D_INNER) / 256, blk, 0, stream>>>(
        xz_il, conv_w, conv_b, u_bf);

    // 3) x_dbl = u @ x_proj_w^T   (split-K=8, fp32 partials)
    gemm_mfma_bt<0, 0, float>
        <<<dim3(1, M_ROWS / 128, XP_KSPLIT), blk, 0, stream>>>(
        u_bf, xpw_bf, xp_part, nullptr, M_ROWS, 128, D_INNER, XP_KLEN);
    xproj_reduce_kernel<<<(M_ROWS * 24 + 255) / 256, blk, 0, stream>>>(
        xp_part, xdbl, dt_bf);

    // 4) delta = softplus(dt @ dt_proj_w^T + dt_proj_b)  (interleaved bf16 out)
    gemm_mfma_bt<1, 1, unsigned short>
        <<<dim3(D_INNER / 128, M_ROWS / 128, 1), blk, 0, stream>>>(
        dt_bf, dtw_bf, delta_il, dt_proj_b, M_ROWS, D_INNER, DT_RANK, DT_RANK);

    // 5) single-pass fused scan (decoupled lookback)
    scan_fused_kernel<<<N_BATCH * (D_INNER / 256) * N_CHUNK, blk, 0, stream>>>(
        delta_il, u_bf, xdbl, xz_il, A_log, D_param,
        Pws, Qws, Hws, flags, y_bf);

    // 6) out = y @ out_proj_w^T   (split-K=2, fp32 partials)
    gemm_mfma_bt<0, 0, float>
        <<<dim3(D_MODEL / 128, M_ROWS / 128, OP_KSPLIT), blk, 0, stream>>>(
        y_bf, opw_bf, op_part, nullptr, M_ROWS, D_MODEL, D_INNER, OP_KLEN);
    oproj_reduce_kernel<<<(M_ROWS * D_MODEL / 4 + 255) / 256, blk, 0, stream>>>(
        op_part, out);
}

// Round 10
// 372.672 us; speedup vs baseline: 1.8731x; 1.8731x over previous
//
#include <hip/hip_runtime.h>
#include <hip/hip_bf16.h>
#include <math.h>

#define D_MODEL 1024
#define D_STATE 16
#define D_CONV 4
#define D_INNER 2048
#define DT_RANK 64
#define L_SEQ 2048
#define N_BATCH 2
#define M_ROWS (N_BATCH * L_SEQ)   // 4096

#define N_CHUNK 32                 // chunks over L
#define CLEN (L_SEQ / N_CHUNK)     // 64 timesteps per chunk

#define XP_KSPLIT 8
#define XP_KLEN (D_INNER / XP_KSPLIT)  // 256
#define OP_KSPLIT 2
#define OP_KLEN (D_INNER / OP_KSPLIT)  // 1024

typedef __attribute__((ext_vector_type(8))) __bf16 bf16x8;
typedef __attribute__((ext_vector_type(4))) float f32x4;

__device__ __forceinline__ unsigned short f2b(float f) {
    unsigned int u = __float_as_uint(f);
    unsigned int r = (u + 0x7fffu + ((u >> 16) & 1u)) >> 16;   // RNE
    return (unsigned short)r;
}
__device__ __forceinline__ float b2f(unsigned short s) {
    return __uint_as_float((unsigned int)s << 16);
}
// fast softplus: max(x,0) + log(1+exp(-|x|)), branch-free
__device__ __forceinline__ float softplus_fast(float x) {
    const float ax = fabsf(x);
    return fmaxf(x, 0.f) + __logf(1.f + __expf(-ax));
}

// addrspace casts for global_load_lds
#define AS1G(p) ((const __attribute__((address_space(1))) void*)(uintptr_t)(p))
#define AS3L(p) ((__attribute__((address_space(3))) void*)(unsigned int)(uintptr_t)(p))

// ---------------------------------------------------------------------------
// Fused fp32 -> bf16 cast of all tensors (one launch).
// x_proj_w is padded 96 -> 128 rows (zeros).
// ---------------------------------------------------------------------------
#define N4_HS (M_ROWS * D_MODEL / 4)          // 1048576
#define N4_IP (2 * D_INNER * D_MODEL / 4)     // 2097152
#define N4_OP (D_MODEL * D_INNER / 4)         // 524288
#define N4_XP (128 * D_INNER / 4)             // 65536 (padded)
#define N4_DT (D_INNER * DT_RANK / 4)         // 32768
#define N4_ALL (N4_HS + N4_IP + N4_OP + N4_XP + N4_DT)

__device__ __forceinline__ void cvt4(const float* s, unsigned short* d, int i) {
    const float4 f = ((const float4*)s)[i];
    ushort4 o;
    o.x = f2b(f.x); o.y = f2b(f.y); o.z = f2b(f.z); o.w = f2b(f.w);
    ((ushort4*)d)[i] = o;
}

__global__ __launch_bounds__(256) void cvt_all_kernel(
    const float* __restrict__ hs,  const float* __restrict__ ipw,
    const float* __restrict__ opw, const float* __restrict__ xpw,
    const float* __restrict__ dtw,
    unsigned short* __restrict__ hs_bf,  unsigned short* __restrict__ ipw_bf,
    unsigned short* __restrict__ opw_bf, unsigned short* __restrict__ xpw_bf,
    unsigned short* __restrict__ dtw_bf)
{
    int i = blockIdx.x * 256 + threadIdx.x;
    if (i < N4_HS) { cvt4(hs, hs_bf, i); return; }
    i -= N4_HS;
    if (i < N4_IP) { cvt4(ipw, ipw_bf, i); return; }
    i -= N4_IP;
    if (i < N4_OP) { cvt4(opw, opw_bf, i); return; }
    i -= N4_OP;
    if (i < N4_XP) {
        const int row = (i * 4) >> 11;   // /2048
        ushort4 o;
        if (row < 96) {
            const float4 f = ((const float4*)xpw)[i];
            o.x = f2b(f.x); o.y = f2b(f.y); o.z = f2b(f.z); o.w = f2b(f.w);
        } else { o.x = o.y = o.z = o.w = 0; }
        ((ushort4*)xpw_bf)[i] = o;
        return;
    }
    i -= N4_XP;
    if (i < N4_DT) cvt4(dtw, dtw_bf, i);
}

// ---------------------------------------------------------------------------
// bf16 MFMA GEMM (m97 structure): C[M,N] = A[M,K]*B[N,K]^T.
// MODE 0: plain.  MODE 1: softplus(acc + bias[col]).
// LAYOUT 0: CT out (fp32 partials), row-major.
// LAYOUT 1: bf16 out, m4-interleaved: off(m,c) = ((m>>2)*N + c)*4 + (m&3)
//           -> each lane's 4-row acc column packs into ONE coalesced b64 store.
// Split-K: blockIdx.z selects K-chunk, C += z*M*N (LAYOUT 0 only).
// ---------------------------------------------------------------------------
template <int MODE, int LAYOUT, typename CT>
__global__ __launch_bounds__(256) void gemm_mfma_bt(
    const unsigned short* __restrict__ A, const unsigned short* __restrict__ B,
    CT* __restrict__ C, const float* __restrict__ bias,
    int M, int N, int K, int k_len)
{
    __shared__ unsigned short As[128 * 32];
    __shared__ unsigned short Bs[128 * 32];

    const int tid  = threadIdx.x;
    const int wave = tid >> 6;
    const int lane = tid & 63;
    const int row0 = blockIdx.y * 128;
    const int col0 = blockIdx.x * 128;
    const int kbeg = blockIdx.z * k_len;
    C += (size_t)blockIdx.z * M * N;
    const int wr = (wave >> 1) * 64;
    const int wc = (wave & 1) * 64;
    const int lm = lane & 15;
    const int kg = (lane >> 4) * 8;

    f32x4 acc[4][4];
    #pragma unroll
    for (int i = 0; i < 4; ++i)
        #pragma unroll
        for (int j = 0; j < 4; ++j)
            acc[i][j] = (f32x4){0.f, 0.f, 0.f, 0.f};

    const int c0 = tid;
    const int c1 = tid + 256;
    const int r0_ = c0 >> 2, kq0 = (c0 & 3) * 8;
    const int r1_ = c1 >> 2, kq1 = (c1 & 3) * 8;
    unsigned short* lA0 = As + wave * 512;
    unsigned short* lA1 = As + 2048 + wave * 512;
    unsigned short* lB0 = Bs + wave * 512;
    unsigned short* lB1 = Bs + 2048 + wave * 512;

    for (int k0 = kbeg; k0 < kbeg + k_len; k0 += 32) {
        __syncthreads();
        __builtin_amdgcn_global_load_lds(AS1G(A + (size_t)(row0 + r0_) * K + k0 + kq0), AS3L(lA0), 16, 0, 0);
        __builtin_amdgcn_global_load_lds(AS1G(A + (size_t)(row0 + r1_) * K + k0 + kq1), AS3L(lA1), 16, 0, 0);
        __builtin_amdgcn_global_load_lds(AS1G(B + (size_t)(col0 + r0_) * K + k0 + kq0), AS3L(lB0), 16, 0, 0);
        __builtin_amdgcn_global_load_lds(AS1G(B + (size_t)(col0 + r1_) * K + k0 + kq1), AS3L(lB1), 16, 0, 0);
        __syncthreads();

        bf16x8 af[4], bf[4];
        #pragma unroll
        for (int i = 0; i < 4; ++i) {
            af[i] = *(const bf16x8*)&As[(wr + i * 16 + lm) * 32 + kg];
            bf[i] = *(const bf16x8*)&Bs[(wc + i * 16 + lm) * 32 + kg];
        }
        #pragma unroll
        for (int i = 0; i < 4; ++i)
            #pragma unroll
            for (int j = 0; j < 4; ++j)
                acc[i][j] = __builtin_amdgcn_mfma_f32_16x16x32_bf16(af[i], bf[j], acc[i][j], 0, 0, 0);
    }

    // C/D mapping: col = lane&15, row = (lane>>4)*4 + reg
    const int quad = lane >> 4;
    if constexpr (LAYOUT == 1) {
        #pragma unroll
        for (int i = 0; i < 4; ++i) {
            const int r4 = (row0 + wr + i * 16) / 4 + quad;   // row>>2
            #pragma unroll
            for (int j = 0; j < 4; ++j) {
                const int cc = col0 + wc + j * 16 + lm;
                const float bv = (MODE == 1) ? bias[cc] : 0.f;
                float v0 = acc[i][j][0], v1 = acc[i][j][1];
                float v2 = acc[i][j][2], v3 = acc[i][j][3];
                if (MODE == 1) {
                    v0 = softplus_fast(v0 + bv); v1 = softplus_fast(v1 + bv);
                    v2 = softplus_fast(v2 + bv); v3 = softplus_fast(v3 + bv);
                }
                ushort4 o;
                o.x = f2b(v0); o.y = f2b(v1); o.z = f2b(v2); o.w = f2b(v3);
                *(ushort4*)((unsigned short*)C + ((size_t)r4 * N + cc) * 4) = o;
            }
        }
    } else {
        #pragma unroll
        for (int j = 0; j < 4; ++j) {
            const int cc = col0 + wc + j * 16 + lm;
            const float bv = (MODE == 1) ? bias[cc] : 0.f;
            #pragma unroll
            for (int i = 0; i < 4; ++i) {
                const int r = row0 + wr + i * 16 + quad * 4;
                #pragma unroll
                for (int v = 0; v < 4; ++v) {
                    float val = acc[i][j][v];
                    if (MODE == 1) val = softplus_fast(val + bv);
                    C[(size_t)(r + v) * N + cc] = (CT)val;
                }
            }
        }
    }
}

// reduce x_proj split-K partials [XP_KSPLIT][M][128] -> xdbl [M][96] fp32
// and dt_bf [M][64] bf16.
__global__ __launch_bounds__(256) void xproj_reduce_kernel(
    const float* __restrict__ part, float* __restrict__ xdbl,
    unsigned short* __restrict__ dt_bf)
{
    const int i = blockIdx.x * 256 + threadIdx.x;   // over M * 24
    if (i >= M_ROWS * 24) return;
    const int m  = i / 24;
    const int j4 = (i - m * 24) * 4;
    f32x4 s = *(const f32x4*)(part + (size_t)m * 128 + j4);
    #pragma unroll
    for (int ks = 1; ks < XP_KSPLIT; ++ks)
        s += *(const f32x4*)(part + (size_t)ks * M_ROWS * 128 + (size_t)m * 128 + j4);
    *(f32x4*)(xdbl + (size_t)m * 96 + j4) = s;
    if (j4 < DT_RANK) {
        ushort4 o;
        o.x = f2b(s.x); o.y = f2b(s.y); o.z = f2b(s.z); o.w = f2b(s.w);
        *(ushort4*)(dt_bf + (size_t)m * DT_RANK + j4) = o;
    }
}

// reduce out_proj split-K partials [OP_KSPLIT][M][D_MODEL] -> out (fp32)
__global__ __launch_bounds__(256) void oproj_reduce_kernel(
    const float* __restrict__ part, float* __restrict__ out)
{
    const int i = blockIdx.x * 256 + threadIdx.x;   // over M*D_MODEL/4
    if (i >= M_ROWS * D_MODEL / 4) return;
    f32x4 s = ((const f32x4*)part)[i];
    #pragma unroll
    for (int ks = 1; ks < OP_KSPLIT; ++ks)
        s += ((const f32x4*)part)[(size_t)ks * (M_ROWS * D_MODEL / 4) + i];
    ((f32x4*)out)[i] = s;
}

// ---------------------------------------------------------------------------
// Depthwise causal conv (width 4) + bias + SiLU.  Reads x half of the
// m4-interleaved xz; writes u row-major bf16.
// ---------------------------------------------------------------------------
__global__ __launch_bounds__(256) void conv_silu_kernel(
    const unsigned short* __restrict__ xz_il, const float* __restrict__ conv_w,
    const float* __restrict__ conv_b, unsigned short* __restrict__ u_bf)
{
    const int idx = blockIdx.x * 256 + threadIdx.x;
    const int c  = idx & (D_INNER - 1);
    const int ml = idx >> 11;
    const int l  = ml & (L_SEQ - 1);
    float acc = conv_b[c];
    const float* w = conv_w + c * D_CONV;
    #pragma unroll
    for (int j = 0; j < D_CONV; ++j) {
        const int ll = l - (D_CONV - 1) + j;
        if (ll >= 0) {
            const int mm = ml - (D_CONV - 1) + j;
            const size_t off = ((size_t)(mm >> 2) * (2 * D_INNER) + c) * 4 + (mm & 3);
            acc = fmaf(b2f(xz_il[off]), w[j], acc);
        }
    }
    const float uv = acc / (1.f + __expf(-acc));
    u_bf[(size_t)ml * D_INNER + c] = f2b(uv);
}

// ---------------------------------------------------------------------------
// Sequential-register selective scan (round-8 proven structure).
// One lane owns one d channel + 16 states in registers.
// delta: m4-interleaved bf16; u row-major bf16; z from interleaved xz;
// B/C: wave-uniform s_loads.  No inter-block sync.
// PHASE 0: P = prod dA, Q = local scan from 0.   PHASE 1: scan from Hin -> y.
// ---------------------------------------------------------------------------
template <int PHASE>
__global__ __launch_bounds__(256) void scan_seq_kernel(
    const unsigned short* __restrict__ delta_il,
    const unsigned short* __restrict__ u_bf,
    const float* __restrict__ xdbl,
    const unsigned short* __restrict__ xz_il,
    const float* __restrict__ A_log, const float* __restrict__ Dp,
    float* __restrict__ P, float* __restrict__ Q,
    const float* __restrict__ Hin, unsigned short* __restrict__ y)
{
    const int bid  = blockIdx.x;
    const int c    = bid & (N_CHUNK - 1);
    const int rest = bid >> 5;
    const int b    = rest >> 3;
    const int dgrp = rest & 7;
    const int d    = dgrp * 256 + threadIdx.x;
    const int t0   = c * CLEN;

    float nA[16];
    #pragma unroll
    for (int k = 0; k < 4; ++k) {
        const float4 a4 = *(const float4*)(A_log + (size_t)d * 16 + k * 4);
        nA[4 * k + 0] = -__expf(a4.x);
        nA[4 * k + 1] = -__expf(a4.y);
        nA[4 * k + 2] = -__expf(a4.z);
        nA[4 * k + 3] = -__expf(a4.w);
    }

    const size_t sbase = (((size_t)(b * N_CHUNK + c)) << 15) + ((size_t)d << 4);

    float h[16], Pacc[16];
    if (PHASE == 0) {
        #pragma unroll
        for (int n = 0; n < 16; ++n) { h[n] = 0.f; Pacc[n] = 1.f; }
    } else {
        #pragma unroll
        for (int k = 0; k < 4; ++k) {
            const float4 h4 = *(const float4*)(Hin + sbase + k * 4);
            h[4 * k + 0] = h4.x; h[4 * k + 1] = h4.y;
            h[4 * k + 2] = h4.z; h[4 * k + 3] = h4.w;
        }
    }
    const float Dd = (PHASE == 1) ? Dp[d] : 0.f;

    #pragma unroll 2
    for (int t = 0; t < CLEN; ++t) {
        const size_t m = (size_t)b * L_SEQ + t0 + t;
        const float dt_v = b2f(delta_il[((m >> 2) * D_INNER + d) * 4 + (m & 3)]);
        const float u_v  = b2f(u_bf[m * D_INNER + d]);
        const float dtu  = dt_v * u_v;
        const float* sB = xdbl + m * 96 + DT_RANK;   // wave-uniform -> s_load
        const float* sC = sB + D_STATE;

        float v = u_v * Dd;
        #pragma unroll
        for (int n = 0; n < 16; ++n) {
            const float dA = __expf(dt_v * nA[n]);
            if (PHASE == 0) Pacc[n] *= dA;
            h[n] = fmaf(dA, h[n], dtu * sB[n]);
            if (PHASE == 1) v = fmaf(h[n], sC[n], v);
        }
        if (PHASE == 1) {
            const float z = b2f(xz_il[((m >> 2) * (2 * D_INNER) + D_INNER + d) * 4 + (m & 3)]);
            const float sig = 1.f / (1.f + __expf(-z));
            y[m * D_INNER + d] = f2b(v * z * sig);
        }
    }

    if (PHASE == 0) {
        #pragma unroll
        for (int k = 0; k < 4; ++k) {
            *(float4*)(P + sbase + k * 4) =
                make_float4(Pacc[4*k], Pacc[4*k+1], Pacc[4*k+2], Pacc[4*k+3]);
            *(float4*)(Q + sbase + k * 4) =
                make_float4(h[4*k], h[4*k+1], h[4*k+2], h[4*k+3]);
        }
    }
}

// ---------------------------------------------------------------------------
// Sequential chunk composition: h_in[c] for each (b,d,n).
// ---------------------------------------------------------------------------
__global__ __launch_bounds__(256) void scan_combine_kernel(
    const float* __restrict__ P, const float* __restrict__ Q,
    float* __restrict__ Hin)
{
    const int idx = blockIdx.x * 256 + threadIdx.x;
    const int b   = idx >> 15;
    const int dn  = idx & 32767;
    float h = 0.f;
    #pragma unroll
    for (int c = 0; c < N_CHUNK; ++c) {
        const size_t o = ((size_t)(b * N_CHUNK + c) << 15) + dn;
        Hin[o] = h;
        h = fmaf(P[o], h, Q[o]);
    }
}

// ---------------------------------------------------------------------------
// Launch
// ---------------------------------------------------------------------------
extern "C" void kernel_launch(void* const* d_in, const int* in_sizes, int n_in,
                              void* d_out, int out_size, void* d_ws, size_t ws_size,
                              hipStream_t stream)
{
    const float* hs        = (const float*)d_in[0];
    const float* in_proj_w = (const float*)d_in[1];
    const float* conv_w    = (const float*)d_in[2];
    const float* conv_b    = (const float*)d_in[3];
    const float* x_proj_w  = (const float*)d_in[4];
    const float* dt_proj_w = (const float*)d_in[5];
    const float* dt_proj_b = (const float*)d_in[6];
    const float* A_log     = (const float*)d_in[7];
    const float* D_param   = (const float*)d_in[8];
    const float* out_proj_w= (const float*)d_in[9];
    float* out = (float*)d_out;

    // ---- workspace layout ----
    unsigned short* xz_il = (unsigned short*)d_ws;                       // 33.5MB (interleaved)
    unsigned short* u_bf  = xz_il + (size_t)M_ROWS * 2 * D_INNER;        // 16.8MB
    float* xdbl           = (float*)(u_bf + (size_t)M_ROWS * D_INNER);   // 1.6MB
    unsigned short* dt_bf = (unsigned short*)(xdbl + (size_t)M_ROWS * 96); // 0.5MB
    float* delta_region   = (float*)(dt_bf + (size_t)M_ROWS * DT_RANK);  // reserve 33.5MB
    unsigned short* delta_il = (unsigned short*)delta_region;            // uses 16.8MB (interleaved)
    float* Pws = delta_region + (size_t)M_ROWS * D_INNER;                // 8.4MB
    float* Qws = Pws + (size_t)N_BATCH * N_CHUNK * D_INNER * 16;         // 8.4MB
    float* Hin = Qws + (size_t)N_BATCH * N_CHUNK * D_INNER * 16;         // 8.4MB
    unsigned short* opw_bf = (unsigned short*)(Hin + (size_t)N_BATCH * N_CHUNK * D_INNER * 16);
    unsigned short* y_bf   = opw_bf + (size_t)D_MODEL * D_INNER;         // 16.8MB
    unsigned short* xpw_bf = y_bf   + (size_t)M_ROWS * D_INNER;          // 0.5MB
    unsigned short* dtw_bf = xpw_bf + (size_t)128 * D_INNER;             // 0.26MB
    // aliases (stream-ordered, non-overlapping lifetimes):
    unsigned short* hs_bf  = (unsigned short*)delta_region;      // dead after in_proj
    unsigned short* ipw_bf = hs_bf + (size_t)M_ROWS * D_MODEL;
    float* xp_part = (float*)y_bf;     // [8][4096][128] f32 = 16.8MB, dead after xproj_reduce
    float* op_part = (float*)xz_il;    // [2][4096][1024] f32 = 33.5MB, xz dead after scan

    const dim3 blk(256);

    // 0) fused casts
    cvt_all_kernel<<<(N4_ALL + 255) / 256, blk, 0, stream>>>(
        hs, in_proj_w, out_proj_w, x_proj_w, dt_proj_w,
        hs_bf, ipw_bf, opw_bf, xpw_bf, dtw_bf);

    // 1) xz = hs @ in_proj_w^T   (bf16 MFMA, interleaved bf16 out)
    gemm_mfma_bt<0, 1, unsigned short>
        <<<dim3((2 * D_INNER) / 128, M_ROWS / 128, 1), blk, 0, stream>>>(
        hs_bf, ipw_bf, xz_il, nullptr, M_ROWS, 2 * D_INNER, D_MODEL, D_MODEL);

    // 2) u = silu(causal_conv(x) + conv_b)
    conv_silu_kernel<<<(M_ROWS * D_INNER) / 256, blk, 0, stream>>>(
        xz_il, conv_w, conv_b, u_bf);

    // 3) x_dbl = u @ x_proj_w^T   (split-K=8, fp32 partials)
    gemm_mfma_bt<0, 0, float>
        <<<dim3(1, M_ROWS / 128, XP_KSPLIT), blk, 0, stream>>>(
        u_bf, xpw_bf, xp_part, nullptr, M_ROWS, 128, D_INNER, XP_KLEN);
    xproj_reduce_kernel<<<(M_ROWS * 24 + 255) / 256, blk, 0, stream>>>(
        xp_part, xdbl, dt_bf);

    // 4) delta = softplus(dt @ dt_proj_w^T + dt_proj_b)  (interleaved bf16 out)
    gemm_mfma_bt<1, 1, unsigned short>
        <<<dim3(D_INNER / 128, M_ROWS / 128, 1), blk, 0, stream>>>(
        dt_bf, dtw_bf, delta_il, dt_proj_b, M_ROWS, D_INNER, DT_RANK, DT_RANK);

    // 5) chunked selective scan (register-sequential, 3 dispatches, no sync)
    const int scan_blocks = N_BATCH * (D_INNER / 256) * N_CHUNK;  // 512
    scan_seq_kernel<0><<<scan_blocks, blk, 0, stream>>>(
        delta_il, u_bf, xdbl, xz_il, A_log, D_param, Pws, Qws, nullptr, nullptr);
    scan_combine_kernel<<<(N_BATCH * D_INNER * 16) / 256, blk, 0, stream>>>(
        Pws, Qws, Hin);
    scan_seq_kernel<1><<<scan_blocks, blk, 0, stream>>>(
        delta_il, u_bf, xdbl, xz_il, A_log, D_param, nullptr, nullptr, Hin, y_bf);

    // 6) out = y @ out_proj_w^T   (split-K=2, fp32 partials)
    gemm_mfma_bt<0, 0, float>
        <<<dim3(D_MODEL / 128, M_ROWS / 128, OP_KSPLIT), blk, 0, stream>>>(
        y_bf, opw_bf, op_part, nullptr, M_ROWS, D_MODEL, D_INNER, OP_KLEN);
    oproj_reduce_kernel<<<(M_ROWS * D_MODEL / 4 + 255) / 256, blk, 0, stream>>>(
        op_part, out);
}

// Round 11
// 362.953 us; speedup vs baseline: 1.9233x; 1.0268x over previous
//
#include <hip/hip_runtime.h>
#include <hip/hip_bf16.h>
#include <math.h>

#define D_MODEL 1024
#define D_STATE 16
#define D_CONV 4
#define D_INNER 2048
#define DT_RANK 64
#define L_SEQ 2048
#define N_BATCH 2
#define M_ROWS (N_BATCH * L_SEQ)   // 4096

#define N_CHUNK 64                 // chunks over L
#define CLEN (L_SEQ / N_CHUNK)     // 32 timesteps per chunk

#define XP_KSPLIT 8
#define XP_KLEN (D_INNER / XP_KSPLIT)  // 256
#define OP_KSPLIT 2
#define OP_KLEN (D_INNER / OP_KSPLIT)  // 1024

typedef __attribute__((ext_vector_type(8))) __bf16 bf16x8;
typedef __attribute__((ext_vector_type(4))) float f32x4;

__device__ __forceinline__ unsigned short f2b(float f) {
    unsigned int u = __float_as_uint(f);
    unsigned int r = (u + 0x7fffu + ((u >> 16) & 1u)) >> 16;   // RNE
    return (unsigned short)r;
}
__device__ __forceinline__ float b2f(unsigned short s) {
    return __uint_as_float((unsigned int)s << 16);
}
// fast softplus: max(x,0) + log(1+exp(-|x|)), branch-free
__device__ __forceinline__ float softplus_fast(float x) {
    const float ax = fabsf(x);
    return fmaxf(x, 0.f) + __logf(1.f + __expf(-ax));
}

// addrspace casts for global_load_lds
#define AS1G(p) ((const __attribute__((address_space(1))) void*)(uintptr_t)(p))
#define AS3L(p) ((__attribute__((address_space(3))) void*)(unsigned int)(uintptr_t)(p))

// ---------------------------------------------------------------------------
// Fused fp32 -> bf16 cast of all tensors (one launch).
// x_proj_w is padded 96 -> 128 rows (zeros).
// ---------------------------------------------------------------------------
#define N4_HS (M_ROWS * D_MODEL / 4)          // 1048576
#define N4_IP (2 * D_INNER * D_MODEL / 4)     // 2097152
#define N4_OP (D_MODEL * D_INNER / 4)         // 524288
#define N4_XP (128 * D_INNER / 4)             // 65536 (padded)
#define N4_DT (D_INNER * DT_RANK / 4)         // 32768
#define N4_ALL (N4_HS + N4_IP + N4_OP + N4_XP + N4_DT)

__device__ __forceinline__ void cvt4(const float* s, unsigned short* d, int i) {
    const float4 f = ((const float4*)s)[i];
    ushort4 o;
    o.x = f2b(f.x); o.y = f2b(f.y); o.z = f2b(f.z); o.w = f2b(f.w);
    ((ushort4*)d)[i] = o;
}

__global__ __launch_bounds__(256) void cvt_all_kernel(
    const float* __restrict__ hs,  const float* __restrict__ ipw,
    const float* __restrict__ opw, const float* __restrict__ xpw,
    const float* __restrict__ dtw,
    unsigned short* __restrict__ hs_bf,  unsigned short* __restrict__ ipw_bf,
    unsigned short* __restrict__ opw_bf, unsigned short* __restrict__ xpw_bf,
    unsigned short* __restrict__ dtw_bf)
{
    int i = blockIdx.x * 256 + threadIdx.x;
    if (i < N4_HS) { cvt4(hs, hs_bf, i); return; }
    i -= N4_HS;
    if (i < N4_IP) { cvt4(ipw, ipw_bf, i); return; }
    i -= N4_IP;
    if (i < N4_OP) { cvt4(opw, opw_bf, i); return; }
    i -= N4_OP;
    if (i < N4_XP) {
        const int row = (i * 4) >> 11;   // /2048
        ushort4 o;
        if (row < 96) {
            const float4 f = ((const float4*)xpw)[i];
            o.x = f2b(f.x); o.y = f2b(f.y); o.z = f2b(f.z); o.w = f2b(f.w);
        } else { o.x = o.y = o.z = o.w = 0; }
        ((ushort4*)xpw_bf)[i] = o;
        return;
    }
    i -= N4_XP;
    if (i < N4_DT) cvt4(dtw, dtw_bf, i);
}

// ---------------------------------------------------------------------------
// bf16 MFMA GEMM (m97 structure): C[M,N] = A[M,K]*B[N,K]^T.
// MODE 0: plain.  MODE 1: softplus(acc + bias[col]).
// LAYOUT 0: CT out (fp32 partials), row-major.
// LAYOUT 1: bf16 out, m4-interleaved: off(m,c) = ((m>>2)*N + c)*4 + (m&3)
//           -> each lane's 4-row acc column packs into ONE coalesced b64 store.
// Split-K: blockIdx.z selects K-chunk, C += z*M*N (LAYOUT 0 only).
// ---------------------------------------------------------------------------
template <int MODE, int LAYOUT, typename CT>
__global__ __launch_bounds__(256) void gemm_mfma_bt(
    const unsigned short* __restrict__ A, const unsigned short* __restrict__ B,
    CT* __restrict__ C, const float* __restrict__ bias,
    int M, int N, int K, int k_len)
{
    __shared__ unsigned short As[128 * 32];
    __shared__ unsigned short Bs[128 * 32];

    const int tid  = threadIdx.x;
    const int wave = tid >> 6;
    const int lane = tid & 63;
    const int row0 = blockIdx.y * 128;
    const int col0 = blockIdx.x * 128;
    const int kbeg = blockIdx.z * k_len;
    C += (size_t)blockIdx.z * M * N;
    const int wr = (wave >> 1) * 64;
    const int wc = (wave & 1) * 64;
    const int lm = lane & 15;
    const int kg = (lane >> 4) * 8;

    f32x4 acc[4][4];
    #pragma unroll
    for (int i = 0; i < 4; ++i)
        #pragma unroll
        for (int j = 0; j < 4; ++j)
            acc[i][j] = (f32x4){0.f, 0.f, 0.f, 0.f};

    const int c0 = tid;
    const int c1 = tid + 256;
    const int r0_ = c0 >> 2, kq0 = (c0 & 3) * 8;
    const int r1_ = c1 >> 2, kq1 = (c1 & 3) * 8;
    unsigned short* lA0 = As + wave * 512;
    unsigned short* lA1 = As + 2048 + wave * 512;
    unsigned short* lB0 = Bs + wave * 512;
    unsigned short* lB1 = Bs + 2048 + wave * 512;

    for (int k0 = kbeg; k0 < kbeg + k_len; k0 += 32) {
        __syncthreads();
        __builtin_amdgcn_global_load_lds(AS1G(A + (size_t)(row0 + r0_) * K + k0 + kq0), AS3L(lA0), 16, 0, 0);
        __builtin_amdgcn_global_load_lds(AS1G(A + (size_t)(row0 + r1_) * K + k0 + kq1), AS3L(lA1), 16, 0, 0);
        __builtin_amdgcn_global_load_lds(AS1G(B + (size_t)(col0 + r0_) * K + k0 + kq0), AS3L(lB0), 16, 0, 0);
        __builtin_amdgcn_global_load_lds(AS1G(B + (size_t)(col0 + r1_) * K + k0 + kq1), AS3L(lB1), 16, 0, 0);
        __syncthreads();

        bf16x8 af[4], bf[4];
        #pragma unroll
        for (int i = 0; i < 4; ++i) {
            af[i] = *(const bf16x8*)&As[(wr + i * 16 + lm) * 32 + kg];
            bf[i] = *(const bf16x8*)&Bs[(wc + i * 16 + lm) * 32 + kg];
        }
        #pragma unroll
        for (int i = 0; i < 4; ++i)
            #pragma unroll
            for (int j = 0; j < 4; ++j)
                acc[i][j] = __builtin_amdgcn_mfma_f32_16x16x32_bf16(af[i], bf[j], acc[i][j], 0, 0, 0);
    }

    // C/D mapping: col = lane&15, row = (lane>>4)*4 + reg
    const int quad = lane >> 4;
    if constexpr (LAYOUT == 1) {
        #pragma unroll
        for (int i = 0; i < 4; ++i) {
            const int r4 = (row0 + wr + i * 16) / 4 + quad;   // row>>2
            #pragma unroll
            for (int j = 0; j < 4; ++j) {
                const int cc = col0 + wc + j * 16 + lm;
                const float bv = (MODE == 1) ? bias[cc] : 0.f;
                float v0 = acc[i][j][0], v1 = acc[i][j][1];
                float v2 = acc[i][j][2], v3 = acc[i][j][3];
                if (MODE == 1) {
                    v0 = softplus_fast(v0 + bv); v1 = softplus_fast(v1 + bv);
                    v2 = softplus_fast(v2 + bv); v3 = softplus_fast(v3 + bv);
                }
                ushort4 o;
                o.x = f2b(v0); o.y = f2b(v1); o.z = f2b(v2); o.w = f2b(v3);
                *(ushort4*)((unsigned short*)C + ((size_t)r4 * N + cc) * 4) = o;
            }
        }
    } else {
        #pragma unroll
        for (int j = 0; j < 4; ++j) {
            const int cc = col0 + wc + j * 16 + lm;
            const float bv = (MODE == 1) ? bias[cc] : 0.f;
            #pragma unroll
            for (int i = 0; i < 4; ++i) {
                const int r = row0 + wr + i * 16 + quad * 4;
                #pragma unroll
                for (int v = 0; v < 4; ++v) {
                    float val = acc[i][j][v];
                    if (MODE == 1) val = softplus_fast(val + bv);
                    C[(size_t)(r + v) * N + cc] = (CT)val;
                }
            }
        }
    }
}

// reduce x_proj split-K partials [XP_KSPLIT][M][128] -> xdbl [M][96] fp32
// and dt_bf [M][64] bf16.
__global__ __launch_bounds__(256) void xproj_reduce_kernel(
    const float* __restrict__ part, float* __restrict__ xdbl,
    unsigned short* __restrict__ dt_bf)
{
    const int i = blockIdx.x * 256 + threadIdx.x;   // over M * 24
    if (i >= M_ROWS * 24) return;
    const int m  = i / 24;
    const int j4 = (i - m * 24) * 4;
    f32x4 s = *(const f32x4*)(part + (size_t)m * 128 + j4);
    #pragma unroll
    for (int ks = 1; ks < XP_KSPLIT; ++ks)
        s += *(const f32x4*)(part + (size_t)ks * M_ROWS * 128 + (size_t)m * 128 + j4);
    *(f32x4*)(xdbl + (size_t)m * 96 + j4) = s;
    if (j4 < DT_RANK) {
        ushort4 o;
        o.x = f2b(s.x); o.y = f2b(s.y); o.z = f2b(s.z); o.w = f2b(s.w);
        *(ushort4*)(dt_bf + (size_t)m * DT_RANK + j4) = o;
    }
}

// reduce out_proj split-K partials [OP_KSPLIT][M][D_MODEL] -> out (fp32)
__global__ __launch_bounds__(256) void oproj_reduce_kernel(
    const float* __restrict__ part, float* __restrict__ out)
{
    const int i = blockIdx.x * 256 + threadIdx.x;   // over M*D_MODEL/4
    if (i >= M_ROWS * D_MODEL / 4) return;
    f32x4 s = ((const f32x4*)part)[i];
    #pragma unroll
    for (int ks = 1; ks < OP_KSPLIT; ++ks)
        s += ((const f32x4*)part)[(size_t)ks * (M_ROWS * D_MODEL / 4) + i];
    ((f32x4*)out)[i] = s;
}

// ---------------------------------------------------------------------------
// Depthwise causal conv (width 4) + bias + SiLU.  Reads x half of the
// m4-interleaved xz; writes u row-major bf16 (for x_proj GEMM) AND
// m4-interleaved bf16 (for the scan's 4-timestep vector loads).
// ---------------------------------------------------------------------------
__global__ __launch_bounds__(256) void conv_silu_kernel(
    const unsigned short* __restrict__ xz_il, const float* __restrict__ conv_w,
    const float* __restrict__ conv_b, unsigned short* __restrict__ u_bf,
    unsigned short* __restrict__ u_il)
{
    const int idx = blockIdx.x * 256 + threadIdx.x;
    const int c  = idx & (D_INNER - 1);
    const int ml = idx >> 11;
    const int l  = ml & (L_SEQ - 1);
    float acc = conv_b[c];
    const float* w = conv_w + c * D_CONV;
    #pragma unroll
    for (int j = 0; j < D_CONV; ++j) {
        const int ll = l - (D_CONV - 1) + j;
        if (ll >= 0) {
            const int mm = ml - (D_CONV - 1) + j;
            const size_t off = ((size_t)(mm >> 2) * (2 * D_INNER) + c) * 4 + (mm & 3);
            acc = fmaf(b2f(xz_il[off]), w[j], acc);
        }
    }
    const float uv = acc / (1.f + __expf(-acc));
    const unsigned short ub = f2b(uv);
    u_bf[(size_t)ml * D_INNER + c] = ub;
    u_il[((size_t)(ml >> 2) * D_INNER + c) * 4 + (ml & 3)] = ub;
}

// ---------------------------------------------------------------------------
// Sequential-register selective scan.  One lane owns one d channel + 16
// states in registers.  delta/u/z all m4-interleaved bf16 -> ONE coalesced
// ushort4 load covers 4 timesteps.  B/C: wave-uniform s_loads (fp32).
// Grid: B * 8 dgrps * N_CHUNK(64) = 1024 blocks (4/CU).  No inter-block sync.
// PHASE 0: P = prod dA, Q = local scan from 0.   PHASE 1: scan from Hin -> y.
// ---------------------------------------------------------------------------
template <int PHASE>
__global__ __launch_bounds__(256) void scan_seq_kernel(
    const unsigned short* __restrict__ delta_il,
    const unsigned short* __restrict__ u_il,
    const float* __restrict__ xdbl,
    const unsigned short* __restrict__ xz_il,
    const float* __restrict__ A_log, const float* __restrict__ Dp,
    float* __restrict__ P, float* __restrict__ Q,
    const float* __restrict__ Hin, unsigned short* __restrict__ y)
{
    const int bid  = blockIdx.x;
    const int c    = bid & (N_CHUNK - 1);
    const int rest = bid >> 6;              // log2(N_CHUNK)=6
    const int b    = rest >> 3;
    const int dgrp = rest & 7;
    const int d    = dgrp * 256 + threadIdx.x;
    const int t0   = c * CLEN;

    float nA[16];
    #pragma unroll
    for (int k = 0; k < 4; ++k) {
        const float4 a4 = *(const float4*)(A_log + (size_t)d * 16 + k * 4);
        nA[4 * k + 0] = -__expf(a4.x);
        nA[4 * k + 1] = -__expf(a4.y);
        nA[4 * k + 2] = -__expf(a4.z);
        nA[4 * k + 3] = -__expf(a4.w);
    }

    const size_t sbase = (((size_t)(b * N_CHUNK + c)) << 15) + ((size_t)d << 4);

    float h[16], Pacc[16];
    if (PHASE == 0) {
        #pragma unroll
        for (int n = 0; n < 16; ++n) { h[n] = 0.f; Pacc[n] = 1.f; }
    } else {
        #pragma unroll
        for (int k = 0; k < 4; ++k) {
            const float4 h4 = *(const float4*)(Hin + sbase + k * 4);
            h[4 * k + 0] = h4.x; h[4 * k + 1] = h4.y;
            h[4 * k + 2] = h4.z; h[4 * k + 3] = h4.w;
        }
    }
    const float Dd = (PHASE == 1) ? Dp[d] : 0.f;

    const int mg0 = (b * L_SEQ + t0) >> 2;   // starting m-group (t0 % 4 == 0)

    #pragma unroll 2
    for (int tg = 0; tg < CLEN / 4; ++tg) {
        const int mg = mg0 + tg;
        unsigned short d4[4], u4[4], z4[4];
        *(ushort4*)d4 = *(const ushort4*)(delta_il + ((size_t)mg * D_INNER + d) * 4);
        *(ushort4*)u4 = *(const ushort4*)(u_il + ((size_t)mg * D_INNER + d) * 4);
        if (PHASE == 1)
            *(ushort4*)z4 = *(const ushort4*)(xz_il + ((size_t)mg * (2 * D_INNER) + D_INNER + d) * 4);

        #pragma unroll
        for (int r = 0; r < 4; ++r) {
            const size_t m = (size_t)mg * 4 + r;
            const float dt_v = b2f(d4[r]);
            const float u_v  = b2f(u4[r]);
            const float dtu  = dt_v * u_v;
            const float* sB = xdbl + m * 96 + DT_RANK;   // wave-uniform -> s_load
            const float* sC = sB + D_STATE;

            float v = u_v * Dd;
            #pragma unroll
            for (int n = 0; n < 16; ++n) {
                const float dA = __expf(dt_v * nA[n]);
                if (PHASE == 0) Pacc[n] *= dA;
                h[n] = fmaf(dA, h[n], dtu * sB[n]);
                if (PHASE == 1) v = fmaf(h[n], sC[n], v);
            }
            if (PHASE == 1) {
                const float z = b2f(z4[r]);
                const float sig = 1.f / (1.f + __expf(-z));
                y[m * D_INNER + d] = f2b(v * z * sig);
            }
        }
    }

    if (PHASE == 0) {
        #pragma unroll
        for (int k = 0; k < 4; ++k) {
            *(float4*)(P + sbase + k * 4) =
                make_float4(Pacc[4*k], Pacc[4*k+1], Pacc[4*k+2], Pacc[4*k+3]);
            *(float4*)(Q + sbase + k * 4) =
                make_float4(h[4*k], h[4*k+1], h[4*k+2], h[4*k+3]);
        }
    }
}

// ---------------------------------------------------------------------------
// Sequential chunk composition: h_in[c] for each (b,d,n).
// ---------------------------------------------------------------------------
__global__ __launch_bounds__(256) void scan_combine_kernel(
    const float* __restrict__ P, const float* __restrict__ Q,
    float* __restrict__ Hin)
{
    const int idx = blockIdx.x * 256 + threadIdx.x;
    const int b   = idx >> 15;
    const int dn  = idx & 32767;
    float h = 0.f;
    #pragma unroll 8
    for (int c = 0; c < N_CHUNK; ++c) {
        const size_t o = ((size_t)(b * N_CHUNK + c) << 15) + dn;
        Hin[o] = h;
        h = fmaf(P[o], h, Q[o]);
    }
}

// ---------------------------------------------------------------------------
// Launch
// ---------------------------------------------------------------------------
extern "C" void kernel_launch(void* const* d_in, const int* in_sizes, int n_in,
                              void* d_out, int out_size, void* d_ws, size_t ws_size,
                              hipStream_t stream)
{
    const float* hs        = (const float*)d_in[0];
    const float* in_proj_w = (const float*)d_in[1];
    const float* conv_w    = (const float*)d_in[2];
    const float* conv_b    = (const float*)d_in[3];
    const float* x_proj_w  = (const float*)d_in[4];
    const float* dt_proj_w = (const float*)d_in[5];
    const float* dt_proj_b = (const float*)d_in[6];
    const float* A_log     = (const float*)d_in[7];
    const float* D_param   = (const float*)d_in[8];
    const float* out_proj_w= (const float*)d_in[9];
    float* out = (float*)d_out;

    // ---- workspace layout ----
    unsigned short* xz_il = (unsigned short*)d_ws;                       // 33.5MB (interleaved)
    unsigned short* u_bf  = xz_il + (size_t)M_ROWS * 2 * D_INNER;        // 16.8MB (row-major)
    unsigned short* u_il  = u_bf + (size_t)M_ROWS * D_INNER;             // 16.8MB (interleaved)
    float* xdbl           = (float*)(u_il + (size_t)M_ROWS * D_INNER);   // 1.6MB
    unsigned short* dt_bf = (unsigned short*)(xdbl + (size_t)M_ROWS * 96); // 0.5MB
    float* delta_region   = (float*)(dt_bf + (size_t)M_ROWS * DT_RANK);  // reserve 33.5MB
    unsigned short* delta_il = (unsigned short*)delta_region;            // uses 16.8MB (interleaved)
    float* Pws = delta_region + (size_t)M_ROWS * D_INNER;                // 16.8MB
    float* Qws = Pws + (size_t)N_BATCH * N_CHUNK * D_INNER * 16;         // 16.8MB
    float* Hin = Qws + (size_t)N_BATCH * N_CHUNK * D_INNER * 16;         // 16.8MB
    unsigned short* opw_bf = (unsigned short*)(Hin + (size_t)N_BATCH * N_CHUNK * D_INNER * 16);
    unsigned short* y_bf   = opw_bf + (size_t)D_MODEL * D_INNER;         // 16.8MB
    unsigned short* xpw_bf = y_bf   + (size_t)M_ROWS * D_INNER;          // 0.5MB
    unsigned short* dtw_bf = xpw_bf + (size_t)128 * D_INNER;             // 0.26MB
    // aliases (stream-ordered, non-overlapping lifetimes):
    unsigned short* hs_bf  = (unsigned short*)delta_region;      // dead after in_proj (25.2<=33.5MB)
    unsigned short* ipw_bf = hs_bf + (size_t)M_ROWS * D_MODEL;
    float* xp_part = (float*)y_bf;     // [8][4096][128] f32 = 16.8MB, dead after xproj_reduce
    float* op_part = (float*)xz_il;    // [2][4096][1024] f32 = 33.5MB, xz dead after scan

    const dim3 blk(256);

    // 0) fused casts
    cvt_all_kernel<<<(N4_ALL + 255) / 256, blk, 0, stream>>>(
        hs, in_proj_w, out_proj_w, x_proj_w, dt_proj_w,
        hs_bf, ipw_bf, opw_bf, xpw_bf, dtw_bf);

    // 1) xz = hs @ in_proj_w^T   (bf16 MFMA, interleaved bf16 out)
    gemm_mfma_bt<0, 1, unsigned short>
        <<<dim3((2 * D_INNER) / 128, M_ROWS / 128, 1), blk, 0, stream>>>(
        hs_bf, ipw_bf, xz_il, nullptr, M_ROWS, 2 * D_INNER, D_MODEL, D_MODEL);

    // 2) u = silu(causal_conv(x) + conv_b)  (row-major + interleaved out)
    conv_silu_kernel<<<(M_ROWS * D_INNER) / 256, blk, 0, stream>>>(
        xz_il, conv_w, conv_b, u_bf, u_il);

    // 3) x_dbl = u @ x_proj_w^T   (split-K=8, fp32 partials)
    gemm_mfma_bt<0, 0, float>
        <<<dim3(1, M_ROWS / 128, XP_KSPLIT), blk, 0, stream>>>(
        u_bf, xpw_bf, xp_part, nullptr, M_ROWS, 128, D_INNER, XP_KLEN);
    xproj_reduce_kernel<<<(M_ROWS * 24 + 255) / 256, blk, 0, stream>>>(
        xp_part, xdbl, dt_bf);

    // 4) delta = softplus(dt @ dt_proj_w^T + dt_proj_b)  (interleaved bf16 out)
    gemm_mfma_bt<1, 1, unsigned short>
        <<<dim3(D_INNER / 128, M_ROWS / 128, 1), blk, 0, stream>>>(
        dt_bf, dtw_bf, delta_il, dt_proj_b, M_ROWS, D_INNER, DT_RANK, DT_RANK);

    // 5) chunked selective scan (register-sequential, vectorized 4-t loads)
    const int scan_blocks = N_BATCH * (D_INNER / 256) * N_CHUNK;  // 1024
    scan_seq_kernel<0><<<scan_blocks, blk, 0, stream>>>(
        delta_il, u_il, xdbl, xz_il, A_log, D_param, Pws, Qws, nullptr, nullptr);
    scan_combine_kernel<<<(N_BATCH * D_INNER * 16) / 256, blk, 0, stream>>>(
        Pws, Qws, Hin);
    scan_seq_kernel<1><<<scan_blocks, blk, 0, stream>>>(
        delta_il, u_il, xdbl, xz_il, A_log, D_param, nullptr, nullptr, Hin, y_bf);

    // 6) out = y @ out_proj_w^T   (split-K=2, fp32 partials)
    gemm_mfma_bt<0, 0, float>
        <<<dim3(D_MODEL / 128, M_ROWS / 128, OP_KSPLIT), blk, 0, stream>>>(
        y_bf, opw_bf, op_part, nullptr, M_ROWS, D_MODEL, D_INNER, OP_KLEN);
    oproj_reduce_kernel<<<(M_ROWS * D_MODEL / 4 + 255) / 256, blk, 0, stream>>>(
        op_part, out);
}